// Round 4
// baseline (309.923 us; speedup 1.0000x reference)
//
#include <hip/hip_runtime.h>
#include <math.h>

// Problem constants (B,N,C fixed by the reference setup).
#define BB 16
#define NN 2048
#define CC 64
#define TPB 256
#define MROWS 32          // pruned rows per block (4 waves x 8 rows)
#define RPW 8             // rows per wave
#define E_CONST 2.71828182845904523536f

// ---------------------------------------------------------------------------
// K_pre: zero the A accumulator (d_out) everywhere; blocks 0..BB-1 also run
// ballot-based kept/pruned compaction for batch b and zero S[b,:].
// ---------------------------------------------------------------------------
__global__ __launch_bounds__(TPB) void k_pre(const float* __restrict__ keep,
                                             float* __restrict__ outz,
                                             float* __restrict__ S,
                                             int* __restrict__ cntP,
                                             int* __restrict__ cntK,
                                             int* __restrict__ listP,
                                             int* __restrict__ listK) {
    const int tid = threadIdx.x, lane = tid & 63;

    float4* o4 = (float4*)outz + (size_t)blockIdx.x * 1024;
    float4 z = {0.0f, 0.0f, 0.0f, 0.0f};
#pragma unroll
    for (int i = 0; i < 4; ++i) o4[i * TPB + tid] = z;

    const int b = blockIdx.x;
    if (b >= BB) return;

    __shared__ int cP, cK;
    if (tid == 0) { cP = 0; cK = 0; }
    __syncthreads();
    for (int i = tid; i < NN; i += TPB) S[b * NN + i] = 0.0f;
    const unsigned long long lt = (lane == 63) ? 0x7fffffffffffffffull
                                               : ((1ull << lane) - 1ull);
#pragma unroll
    for (int it = 0; it < NN / TPB; ++it) {
        int n = it * TPB + tid;
        bool kp = keep[b * NN + n] != 0.0f;
        unsigned long long mk = __ballot(kp);
        int nk = __popcll(mk);
        int bk = 0, bp = 0;
        if (lane == 0) {
            bk = atomicAdd(&cK, nk);
            bp = atomicAdd(&cP, 64 - nk);
        }
        bk = __shfl(bk, 0); bp = __shfl(bp, 0);
        int pk = __popcll(mk & lt);
        if (kp) listK[b * NN + bk + pk] = n;
        else    listP[b * NN + bp + (lane - pk)] = n;
    }
    __syncthreads();
    if (tid == 0) { cntP[b] = cP; cntK[b] = cK; }
}

// ---------------------------------------------------------------------------
// K_pre2 (R1-verified): ONE WAVE PER KEPT TOKEN.
//  - wave loads x[tok*64+lane] (coalesced 256B), norm via 6x shfl_xor,
//    transposed scatter store into colM. b = id&15 -> XCD pinning.
//  - zero-fills [K, K+128): tiler never reads past colp = K+127.
// ---------------------------------------------------------------------------
__global__ __launch_bounds__(TPB) void k_pre2(const float* __restrict__ x,
                                              const int* __restrict__ cntK,
                                              const int* __restrict__ listK,
                                              float* __restrict__ colMf) {
    const int b    = blockIdx.x & 15;
    const int seg  = blockIdx.x >> 4;          // 0..63
    const int lane = threadIdx.x & 63;
    const int wid  = threadIdx.x >> 6;
    const int wave = seg * 4 + wid;            // 0..255 per batch
    const int K    = cntK[b];
    const int Kend = min(NN, K + 128);

    const float* xb = x + (size_t)b * NN * CC;
    float* cf = colMf + (size_t)b * 16 * NN * 4;   // batch's [16][NN] float4

    for (int colp = wave; colp < Kend; colp += 256) {
        float v = 0.0f;
        if (colp < K) {
            int tok = listK[b * NN + colp];
            float xv = xb[(size_t)tok * CC + lane];
            float sq = xv * xv;
#pragma unroll
            for (int off = 32; off; off >>= 1) sq += __shfl_xor(sq, off, 64);
            v = xv / (sqrtf(sq) + 1e-6f);
        }
        // float4 element (k4 = lane>>2, colp), component lane&3
        cf[((size_t)(lane >> 2) * NN + colp) * 4 + (lane & 3)] = v;
    }
}

// ---------------------------------------------------------------------------
// K3: GEMM-argmax. R19: LDS-STAGED cv, shared by the block's 4 waves.
// R1/R2/R3 triangulation: VALUBusy ~42% invariant, dur ~70us at both 2 and
// 4 blocks/CU -> limiter is per-wave private L1 streaming of colM (262KB per
// wave; R1 = 1.07GB through L1 = ~27us service) + vmcnt stalls at low
// waves/SIMD. Fix is the canonical GEMM pattern: global_load_lds width=16
// stages a 4-k4 x 256-col chunk (16KB) once per block, double-buffered
// (32KB LDS); all 4 waves ds_read_b128 it. Global cv traffic /4 (134MB,
// ~13.7us L1-service ~= FMA-issue floor 13.7us).
//  - __syncthreads() supplies the vmcnt(0)+lgkmcnt(0) drain (compiler emits
//    it before s_barrier) -- no inline asm needed.
//  - gll dest is wave-uniform base + lane*16 (linear, G21-correct for our
//    consecutive-lane ds_read pattern -- no swizzle needed, 2-way is free).
//  - FMA order per (row,col) bit-identical to R3: k4 ascending, xyzw order.
//    Argmax/tie semantics untouched.
//  - NO min-waves launch_bounds (R2: (256,8) capped VGPR 32, serialized).
//    Grid-limited 2 blocks/CU -> VGPR headroom to ~128 regardless.
// ---------------------------------------------------------------------------
__device__ __forceinline__ void gll16(const void* g, void* l) {
    __builtin_amdgcn_global_load_lds(
        (const __attribute__((address_space(1))) void*)g,
        (__attribute__((address_space(3))) void*)l, 16, 0, 0);
}

// Wave wid stages k4 = kbase + wid of the tile: W4 groups of 64 cols (1KB).
__device__ __forceinline__ void stage_chunk(const float4* __restrict__ cm,
                                            int cstart, int kbase, int W4,
                                            float4 (*buf)[256],
                                            int wid, int lane) {
    const float4* g = cm + (size_t)(kbase + wid) * NN + cstart + lane;
#pragma unroll
    for (int j = 0; j < 4; ++j)
        if (j < W4) gll16(g + j * 64, &buf[wid][j * 64]);
}

template <int J>
__device__ __forceinline__ void compute_chunk(const float4* __restrict__ x4,
                                              const int* rtok,
                                              const float4 (*buf)[256],
                                              int kbase, float acc[RPW][J],
                                              int lane) {
#pragma unroll
    for (int k4l = 0; k4l < 4; ++k4l) {
        float4 rv[RPW];
#pragma unroll
        for (int r = 0; r < RPW; ++r)           // wave-uniform -> s_load
            rv[r] = x4[(size_t)rtok[r] * 16 + kbase + k4l];
        float4 cv[J];
#pragma unroll
        for (int j = 0; j < J; ++j)             // ds_read_b128, conflict-free
            cv[j] = buf[k4l][j * 64 + lane];
#pragma unroll
        for (int r = 0; r < RPW; ++r)
#pragma unroll
            for (int j = 0; j < J; ++j)
                acc[r][j] = fmaf(rv[r].x, cv[j].x,
                            fmaf(rv[r].y, cv[j].y,
                            fmaf(rv[r].z, cv[j].z,
                            fmaf(rv[r].w, cv[j].w, acc[r][j]))));
    }
}

template <int J>
__device__ __forceinline__ void do_tile(const float4* __restrict__ x4,
                                        const float4* __restrict__ cm,
                                        const int* rtok, int cstart, int K,
                                        int lane, int wid,
                                        float4 (*sbuf)[4][256],
                                        float* tmax, unsigned long long* msk) {
    float acc[RPW][J];
#pragma unroll
    for (int r = 0; r < RPW; ++r)
#pragma unroll
        for (int j = 0; j < J; ++j) acc[r][j] = 0.0f;

    stage_chunk(cm, cstart, 0, J, sbuf[0], wid, lane);
    __syncthreads();                             // chunk 0 resident
#pragma unroll
    for (int c = 0; c < 4; ++c) {
        if (c < 3)                               // prefetch next chunk
            stage_chunk(cm, cstart, (c + 1) * 4, J, sbuf[(c + 1) & 1], wid, lane);
        compute_chunk<J>(x4, rtok, sbuf[c & 1], c * 4, acc, lane);
        __syncthreads();                         // drains vmcnt + read-done
    }

    const int cb0 = cstart >> 6;
#pragma unroll
    for (int r = 0; r < RPW; ++r)
#pragma unroll
        for (int j = 0; j < J; ++j) {
            int colp = cstart + j * 64 + lane;
            float s = (colp < K) ? acc[r][j] : -1.0e30f;
            unsigned long long bit = 1ull << (cb0 + j);
            if (s > tmax[r])       { tmax[r] = s; msk[r] = bit; }
            else if (s == tmax[r])  msk[r] |= bit;
        }
}

__global__ __launch_bounds__(TPB) void k_argmax(
    const float* __restrict__ x,      // [B,N,C]
    const float4* __restrict__ colM,  // [B,16,N] float4
    const int*   __restrict__ cntP,
    const int*   __restrict__ cntK,
    const int*   __restrict__ listP,
    const int*   __restrict__ listK,
    float* __restrict__ S,            // [B,N]   zeroed by k_pre
    float* __restrict__ A) {          // [B,N,C] zeroed by k_pre; aliases d_out

    const int b    = blockIdx.x & 15;
    const int tile = blockIdx.x >> 4;
    const int P = cntP[b], K = cntK[b];
    const int base = tile * MROWS;
    if (base >= P) return;            // whole block exits; no barrier after

    __shared__ float4 sbuf[2][4][256];   // 32 KB double-buffered cv tile

    const int tid = threadIdx.x;
    const int wid = tid >> 6;
    const int lane = tid & 63;

    int rtok[RPW];
#pragma unroll
    for (int r = 0; r < RPW; ++r) {
        int rid = base + wid * RPW + r;
        int tok = (rid < P) ? listP[b * NN + rid] : 0;
        rtok[r] = __builtin_amdgcn_readfirstlane(tok);
    }
    const float4* x4 = (const float4*)(x + (size_t)b * NN * CC);
    const float4* cm = colM + (size_t)b * 16 * NN;

    float              tmax[RPW];
    unsigned long long msk[RPW];
#pragma unroll
    for (int r = 0; r < RPW; ++r) { tmax[r] = -3.0e38f; msk[r] = 0ull; }

    // Adaptive tiling: 256-col tiles while >128 cols remain, then one
    // 128-col epilogue. K is block-uniform -> no barrier divergence.
    int cstart = 0;
    while (cstart < K) {
        int rem = K - cstart;
        if (rem > 128) {
            do_tile<4>(x4, cm, rtok, cstart, K, lane, wid, sbuf, tmax, msk);
            cstart += 256;
        } else {
            do_tile<2>(x4, cm, rtok, cstart, K, lane, wid, sbuf, tmax, msk);
            cstart += 128;
        }
    }

    // ---- edge emission: per wave, per valid row ----
    int nvr = P - base - wid * RPW;
    for (int r = 0; r < RPW; ++r) {
        if (r >= nvr) break;
        float m = tmax[r];
#pragma unroll
        for (int off = 32; off; off >>= 1) m = fmaxf(m, __shfl_xor(m, off, 64));
        int src = rtok[r];
        float xv = x[(size_t)(b * NN + src) * CC + lane];
        float sq = xv * xv;
#pragma unroll
        for (int off = 32; off; off >>= 1) sq += __shfl_xor(sq, off, 64);
        float ivr = 1.0f / (sqrtf(sq) + 1e-6f);
        float wgt = expf(m * ivr);
        unsigned long long bal = __ballot(tmax[r] == m && msk[r] != 0ull);
        while (bal) {
            int sl = __ffsll(bal) - 1;
            bal &= bal - 1;
            unsigned long long mm = __shfl(msk[r], sl);
            while (mm) {
                int cb = __ffsll(mm) - 1;
                mm &= mm - 1;
                int colp = (cb << 6) + sl;
                int dst = listK[b * NN + colp];
                atomicAdd(&A[(size_t)(b * NN + dst) * CC + lane], wgt * xv);
                if (lane == 0) atomicAdd(&S[b * NN + dst], wgt);
            }
        }
    }
}

// ---------------------------------------------------------------------------
// K4: out = (e*x + A) / (e + S).  A aliases d_out (in-place), float4.
// ---------------------------------------------------------------------------
__global__ __launch_bounds__(TPB) void k_finalize(const float* __restrict__ x,
                                                  const float* __restrict__ S,
                                                  float* __restrict__ out) {
    int i = blockIdx.x * TPB + threadIdx.x;
    int row = i >> 4;
    float inv = 1.0f / (E_CONST + S[row]);
    float4 xv = ((const float4*)x)[i];
    float4 av = ((float4*)out)[i];
    float4 o;
    o.x = (xv.x * E_CONST + av.x) * inv;
    o.y = (xv.y * E_CONST + av.y) * inv;
    o.z = (xv.z * E_CONST + av.z) * inv;
    o.w = (xv.w * E_CONST + av.w) * inv;
    ((float4*)out)[i] = o;
}

// ---------------------------------------------------------------------------
extern "C" void kernel_launch(void* const* d_in, const int* in_sizes, int n_in,
                              void* d_out, int out_size, void* d_ws, size_t ws_size,
                              hipStream_t stream) {
    const float* x    = (const float*)d_in[0];
    const float* keep = (const float*)d_in[2];
    float* out = (float*)d_out;

    // ws: (reserved 128KB) | S 128KB | cnts 128B | listP 128KB | listK 128KB | colM 8MB
    char* ws = (char*)d_ws;
    float* S    = (float*)(ws + (128 << 10));
    int*   cntP = (int*)(ws + (256 << 10));
    int*   cntK = cntP + 16;
    int*   listP = (int*)(ws + (256 << 10) + 128);
    int*   listK = listP + BB * NN;
    float* colMf = (float*)(ws + (1 << 20));

    k_pre<<<512, TPB, 0, stream>>>(keep, out, S, cntP, cntK, listP, listK);

    // 1-D grid, b = id&15: colM written on the XCD that k_argmax reads it on.
    k_pre2<<<BB * 64, TPB, 0, stream>>>(x, cntK, listK, colMf);

    // 1-D grid: b = id & 15 (XCD pinning), tile = id >> 4.
    k_argmax<<<(NN / MROWS) * BB, TPB, 0, stream>>>(x, (const float4*)colMf,
                                                    cntP, cntK, listP, listK,
                                                    S, out);

    k_finalize<<<(BB * NN * CC / 4) / TPB, TPB, 0, stream>>>(x, S, out);
}

// Round 5
// 302.338 us; speedup vs baseline: 1.0251x; 1.0251x over previous
//
#include <hip/hip_runtime.h>
#include <math.h>

// Problem constants (B,N,C fixed by the reference setup).
#define BB 16
#define NN 2048
#define CC 64
#define TPB 256
#define MROWS 32          // pruned rows per block (4 waves x 8 rows)  [R20]
#define RPW 8             // rows per wave                             [R20]
#define E_CONST 2.71828182845904523536f

// ---------------------------------------------------------------------------
// K_pre: zero the A accumulator (d_out) everywhere; blocks 0..BB-1 also run
// ballot-based kept/pruned compaction for batch b and zero S[b,:].
// ---------------------------------------------------------------------------
__global__ __launch_bounds__(TPB) void k_pre(const float* __restrict__ keep,
                                             float* __restrict__ outz,
                                             float* __restrict__ S,
                                             int* __restrict__ cntP,
                                             int* __restrict__ cntK,
                                             int* __restrict__ listP,
                                             int* __restrict__ listK) {
    const int tid = threadIdx.x, lane = tid & 63;

    float4* o4 = (float4*)outz + (size_t)blockIdx.x * 1024;
    float4 z = {0.0f, 0.0f, 0.0f, 0.0f};
#pragma unroll
    for (int i = 0; i < 4; ++i) o4[i * TPB + tid] = z;

    const int b = blockIdx.x;
    if (b >= BB) return;

    __shared__ int cP, cK;
    if (tid == 0) { cP = 0; cK = 0; }
    __syncthreads();
    for (int i = tid; i < NN; i += TPB) S[b * NN + i] = 0.0f;
    const unsigned long long lt = (lane == 63) ? 0x7fffffffffffffffull
                                               : ((1ull << lane) - 1ull);
#pragma unroll
    for (int it = 0; it < NN / TPB; ++it) {
        int n = it * TPB + tid;
        bool kp = keep[b * NN + n] != 0.0f;
        unsigned long long mk = __ballot(kp);
        int nk = __popcll(mk);
        int bk = 0, bp = 0;
        if (lane == 0) {
            bk = atomicAdd(&cK, nk);
            bp = atomicAdd(&cP, 64 - nk);
        }
        bk = __shfl(bk, 0); bp = __shfl(bp, 0);
        int pk = __popcll(mk & lt);
        if (kp) listK[b * NN + bk + pk] = n;
        else    listP[b * NN + bp + (lane - pk)] = n;
    }
    __syncthreads();
    if (tid == 0) { cntP[b] = cP; cntK[b] = cK; }
}

// ---------------------------------------------------------------------------
// K_pre2 (R1-verified): ONE WAVE PER KEPT TOKEN.
//  - wave loads x[tok*64+lane] (coalesced 256B), norm via 6x shfl_xor,
//    transposed scatter store into colM. b = id&15 -> XCD pinning.
//  - zero-fills [K, K+128): tiler never reads past colp = K+127.
// ---------------------------------------------------------------------------
__global__ __launch_bounds__(TPB) void k_pre2(const float* __restrict__ x,
                                              const int* __restrict__ cntK,
                                              const int* __restrict__ listK,
                                              float* __restrict__ colMf) {
    const int b    = blockIdx.x & 15;
    const int seg  = blockIdx.x >> 4;          // 0..63
    const int lane = threadIdx.x & 63;
    const int wid  = threadIdx.x >> 6;
    const int wave = seg * 4 + wid;            // 0..255 per batch
    const int K    = cntK[b];
    const int Kend = min(NN, K + 128);

    const float* xb = x + (size_t)b * NN * CC;
    float* cf = colMf + (size_t)b * 16 * NN * 4;   // batch's [16][NN] float4

    for (int colp = wave; colp < Kend; colp += 256) {
        float v = 0.0f;
        if (colp < K) {
            int tok = listK[b * NN + colp];
            float xv = xb[(size_t)tok * CC + lane];
            float sq = xv * xv;
#pragma unroll
            for (int off = 32; off; off >>= 1) sq += __shfl_xor(sq, off, 64);
            v = xv / (sqrtf(sq) + 1e-6f);
        }
        // float4 element (k4 = lane>>2, colp), component lane&3
        cf[((size_t)(lane >> 2) * NN + colp) * 4 + (lane & 3)] = v;
    }
}

// ---------------------------------------------------------------------------
// K3: GEMM-argmax. R20: RPW=8 FOR REAL this time.
// Model (R1/R2/R3 triangulation): VMEM service floor = 27us/(RPW/4); FMA
// floor 13.7us. R3's RPW=8 attempt silently ran at VGPR 52 (allocator chose
// occupancy over ILP; 8-deep b128 streams serialized) -> 71us. R4's LDS
// staging: barrier vmcnt(0) drain every chunk at 2 blocks/CU -> 235us. DEAD.
// This round forces the register shape the model needs:
//  - __launch_bounds__(TPB, 1): permit up to ~512 VGPR. Grid-limited
//    2 blocks/CU means spending 100+ VGPR is free.
//  - explicit cvA/cvB alternating register double-buffer over k4 (STATIC
//    names, no runtime indexing -- rule #20), so 8 b128 stay in flight by
//    construction, not by allocator mood.
//  - FMA chain per (row,col) is k4-ascending, xyzw order: bit-identical to
//    the R1 champion. Argmax/tie semantics untouched.
//  - rv rows: readfirstlane'd index -> scalar s_load, SGPR operands.
//  - adaptive 256/128 col tiles; 64-bit tie mask, bit = colp>>6.
// Expected counters: VGPR 90-130 (<=64 means the hint was ignored -> void);
// Occupancy ~15% is the DESIGN (2 blocks/CU), not a regression.
// ---------------------------------------------------------------------------
template <int J>
__device__ __forceinline__ void tile_body(const float4* __restrict__ x4,
                                          const float4* __restrict__ cm,
                                          const int* rtok, int cstart, int K,
                                          int lane, float* tmax,
                                          unsigned long long* msk) {
    float acc[RPW][J];
#pragma unroll
    for (int r = 0; r < RPW; ++r)
#pragma unroll
        for (int j = 0; j < J; ++j) acc[r][j] = 0.0f;

    const float4* cmk = cm + cstart + lane;     // k4 stride = NN float4

    float4 cvA[J], cvB[J];
#pragma unroll
    for (int j = 0; j < J; ++j) cvA[j] = cmk[j * 64];          // k4 = 0

#pragma unroll
    for (int kk = 0; kk < 8; ++kk) {
        const int kA = 2 * kk, kB = 2 * kk + 1;

#pragma unroll
        for (int j = 0; j < J; ++j)             // issue kB stream
            cvB[j] = cmk[(size_t)kB * NN + j * 64];

        {   // FMA with cvA (k4 = kA) while cvB is in flight
            float4 rv[RPW];
#pragma unroll
            for (int r = 0; r < RPW; ++r)
                rv[r] = x4[(size_t)rtok[r] * 16 + kA];
#pragma unroll
            for (int r = 0; r < RPW; ++r)
#pragma unroll
                for (int j = 0; j < J; ++j)
                    acc[r][j] = fmaf(rv[r].x, cvA[j].x,
                                fmaf(rv[r].y, cvA[j].y,
                                fmaf(rv[r].z, cvA[j].z,
                                fmaf(rv[r].w, cvA[j].w, acc[r][j]))));
        }

        if (kk < 7) {
#pragma unroll
            for (int j = 0; j < J; ++j)         // issue next kA stream
                cvA[j] = cmk[(size_t)(kA + 2) * NN + j * 64];
        }

        {   // FMA with cvB (k4 = kB) while next cvA is in flight
            float4 rv[RPW];
#pragma unroll
            for (int r = 0; r < RPW; ++r)
                rv[r] = x4[(size_t)rtok[r] * 16 + kB];
#pragma unroll
            for (int r = 0; r < RPW; ++r)
#pragma unroll
                for (int j = 0; j < J; ++j)
                    acc[r][j] = fmaf(rv[r].x, cvB[j].x,
                                fmaf(rv[r].y, cvB[j].y,
                                fmaf(rv[r].z, cvB[j].z,
                                fmaf(rv[r].w, cvB[j].w, acc[r][j]))));
        }
    }

    const int cb0 = cstart >> 6;
#pragma unroll
    for (int r = 0; r < RPW; ++r)
#pragma unroll
        for (int j = 0; j < J; ++j) {
            int colp = cstart + j * 64 + lane;
            float s = (colp < K) ? acc[r][j] : -1.0e30f;
            unsigned long long bit = 1ull << (cb0 + j);
            if (s > tmax[r])       { tmax[r] = s; msk[r] = bit; }
            else if (s == tmax[r])  msk[r] |= bit;
        }
}

__global__ __launch_bounds__(TPB, 1) void k_argmax(
    const float* __restrict__ x,      // [B,N,C]
    const float4* __restrict__ colM,  // [B,16,N] float4
    const int*   __restrict__ cntP,
    const int*   __restrict__ cntK,
    const int*   __restrict__ listP,
    const int*   __restrict__ listK,
    float* __restrict__ S,            // [B,N]   zeroed by k_pre
    float* __restrict__ A) {          // [B,N,C] zeroed by k_pre; aliases d_out

    const int b    = blockIdx.x & 15;
    const int tile = blockIdx.x >> 4;
    const int P = cntP[b], K = cntK[b];
    const int base = tile * MROWS;
    if (base >= P) return;

    const int tid = threadIdx.x;
    const int wid = tid >> 6;
    const int lane = tid & 63;

    int rtok[RPW];
#pragma unroll
    for (int r = 0; r < RPW; ++r) {
        int rid = base + wid * RPW + r;
        int tok = (rid < P) ? listP[b * NN + rid] : 0;
        rtok[r] = __builtin_amdgcn_readfirstlane(tok);
    }
    const float4* x4 = (const float4*)(x + (size_t)b * NN * CC);
    const float4* cm = colM + (size_t)b * 16 * NN;

    float              tmax[RPW];
    unsigned long long msk[RPW];
#pragma unroll
    for (int r = 0; r < RPW; ++r) { tmax[r] = -3.0e38f; msk[r] = 0ull; }

    // Adaptive tiling: 256-col tiles while >128 cols remain, then one
    // 128-col epilogue. Branches are wave-uniform (K uniform per block).
    int cstart = 0;
    while (cstart < K) {
        int rem = K - cstart;
        if (rem > 128) {
            tile_body<4>(x4, cm, rtok, cstart, K, lane, tmax, msk);
            cstart += 256;
        } else {
            tile_body<2>(x4, cm, rtok, cstart, K, lane, tmax, msk);
            cstart += 128;
        }
    }

    // ---- edge emission: per wave, per valid row ----
    int nvr = P - base - wid * RPW;
    for (int r = 0; r < RPW; ++r) {
        if (r >= nvr) break;
        float m = tmax[r];
#pragma unroll
        for (int off = 32; off; off >>= 1) m = fmaxf(m, __shfl_xor(m, off, 64));
        int src = rtok[r];
        float xv = x[(size_t)(b * NN + src) * CC + lane];
        float sq = xv * xv;
#pragma unroll
        for (int off = 32; off; off >>= 1) sq += __shfl_xor(sq, off, 64);
        float ivr = 1.0f / (sqrtf(sq) + 1e-6f);
        float wgt = expf(m * ivr);
        unsigned long long bal = __ballot(tmax[r] == m && msk[r] != 0ull);
        while (bal) {
            int sl = __ffsll(bal) - 1;
            bal &= bal - 1;
            unsigned long long mm = __shfl(msk[r], sl);
            while (mm) {
                int cb = __ffsll(mm) - 1;
                mm &= mm - 1;
                int colp = (cb << 6) + sl;
                int dst = listK[b * NN + colp];
                atomicAdd(&A[(size_t)(b * NN + dst) * CC + lane], wgt * xv);
                if (lane == 0) atomicAdd(&S[b * NN + dst], wgt);
            }
        }
    }
}

// ---------------------------------------------------------------------------
// K4: out = (e*x + A) / (e + S).  A aliases d_out (in-place), float4.
// ---------------------------------------------------------------------------
__global__ __launch_bounds__(TPB) void k_finalize(const float* __restrict__ x,
                                                  const float* __restrict__ S,
                                                  float* __restrict__ out) {
    int i = blockIdx.x * TPB + threadIdx.x;
    int row = i >> 4;
    float inv = 1.0f / (E_CONST + S[row]);
    float4 xv = ((const float4*)x)[i];
    float4 av = ((float4*)out)[i];
    float4 o;
    o.x = (xv.x * E_CONST + av.x) * inv;
    o.y = (xv.y * E_CONST + av.y) * inv;
    o.z = (xv.z * E_CONST + av.z) * inv;
    o.w = (xv.w * E_CONST + av.w) * inv;
    ((float4*)out)[i] = o;
}

// ---------------------------------------------------------------------------
extern "C" void kernel_launch(void* const* d_in, const int* in_sizes, int n_in,
                              void* d_out, int out_size, void* d_ws, size_t ws_size,
                              hipStream_t stream) {
    const float* x    = (const float*)d_in[0];
    const float* keep = (const float*)d_in[2];
    float* out = (float*)d_out;

    // ws: (reserved 128KB) | S 128KB | cnts 128B | listP 128KB | listK 128KB | colM 8MB
    char* ws = (char*)d_ws;
    float* S    = (float*)(ws + (128 << 10));
    int*   cntP = (int*)(ws + (256 << 10));
    int*   cntK = cntP + 16;
    int*   listP = (int*)(ws + (256 << 10) + 128);
    int*   listK = listP + BB * NN;
    float* colMf = (float*)(ws + (1 << 20));

    k_pre<<<512, TPB, 0, stream>>>(keep, out, S, cntP, cntK, listP, listK);

    // 1-D grid, b = id&15: colM written on the XCD that k_argmax reads it on.
    k_pre2<<<BB * 64, TPB, 0, stream>>>(x, cntK, listK, colMf);

    // 1-D grid: b = id & 15 (XCD pinning), tile = id >> 4.
    k_argmax<<<(NN / MROWS) * BB, TPB, 0, stream>>>(x, (const float4*)colMf,
                                                    cntP, cntK, listP, listK,
                                                    S, out);

    k_finalize<<<(BB * NN * CC / 4) / TPB, TPB, 0, stream>>>(x, S, out);
}

// Round 6
// 140.839 us; speedup vs baseline: 2.2005x; 2.1467x over previous
//
#include <hip/hip_runtime.h>
#include <math.h>

// Problem constants (B,N,C fixed by the reference setup).
#define BB 16
#define NN 2048
#define CC 64
#define TPB 256
#define MROWS 8           // rows per block, SHARED by all 4 waves (split-K) [R21]
#define E_CONST 2.71828182845904523536f

// ---------------------------------------------------------------------------
// K_pre: zero the A accumulator (d_out) everywhere; blocks 0..BB-1 also run
// ballot-based kept/pruned compaction for batch b and zero S[b,:].
// ---------------------------------------------------------------------------
__global__ __launch_bounds__(TPB) void k_pre(const float* __restrict__ keep,
                                             float* __restrict__ outz,
                                             float* __restrict__ S,
                                             int* __restrict__ cntP,
                                             int* __restrict__ cntK,
                                             int* __restrict__ listP,
                                             int* __restrict__ listK) {
    const int tid = threadIdx.x, lane = tid & 63;

    float4* o4 = (float4*)outz + (size_t)blockIdx.x * 1024;
    float4 z = {0.0f, 0.0f, 0.0f, 0.0f};
#pragma unroll
    for (int i = 0; i < 4; ++i) o4[i * TPB + tid] = z;

    const int b = blockIdx.x;
    if (b >= BB) return;

    __shared__ int cP, cK;
    if (tid == 0) { cP = 0; cK = 0; }
    __syncthreads();
    for (int i = tid; i < NN; i += TPB) S[b * NN + i] = 0.0f;
    const unsigned long long lt = (lane == 63) ? 0x7fffffffffffffffull
                                               : ((1ull << lane) - 1ull);
#pragma unroll
    for (int it = 0; it < NN / TPB; ++it) {
        int n = it * TPB + tid;
        bool kp = keep[b * NN + n] != 0.0f;
        unsigned long long mk = __ballot(kp);
        int nk = __popcll(mk);
        int bk = 0, bp = 0;
        if (lane == 0) {
            bk = atomicAdd(&cK, nk);
            bp = atomicAdd(&cP, 64 - nk);
        }
        bk = __shfl(bk, 0); bp = __shfl(bp, 0);
        int pk = __popcll(mk & lt);
        if (kp) listK[b * NN + bk + pk] = n;
        else    listP[b * NN + bp + (lane - pk)] = n;
    }
    __syncthreads();
    if (tid == 0) { cntP[b] = cP; cntK[b] = cK; }
}

// ---------------------------------------------------------------------------
// K_pre2 (R1-verified): ONE WAVE PER KEPT TOKEN.
//  - wave loads x[tok*64+lane] (coalesced 256B), norm via 6x shfl_xor,
//    transposed scatter store into colM. b = id&15 -> XCD pinning.
//  - zero-fills [K, K+128): tiler never reads past colp = K+127.
// ---------------------------------------------------------------------------
__global__ __launch_bounds__(TPB) void k_pre2(const float* __restrict__ x,
                                              const int* __restrict__ cntK,
                                              const int* __restrict__ listK,
                                              float* __restrict__ colMf) {
    const int b    = blockIdx.x & 15;
    const int seg  = blockIdx.x >> 4;          // 0..63
    const int lane = threadIdx.x & 63;
    const int wid  = threadIdx.x >> 6;
    const int wave = seg * 4 + wid;            // 0..255 per batch
    const int K    = cntK[b];
    const int Kend = min(NN, K + 128);

    const float* xb = x + (size_t)b * NN * CC;
    float* cf = colMf + (size_t)b * 16 * NN * 4;   // batch's [16][NN] float4

    for (int colp = wave; colp < Kend; colp += 256) {
        float v = 0.0f;
        if (colp < K) {
            int tok = listK[b * NN + colp];
            float xv = xb[(size_t)tok * CC + lane];
            float sq = xv * xv;
#pragma unroll
            for (int off = 32; off; off >>= 1) sq += __shfl_xor(sq, off, 64);
            v = xv / (sqrtf(sq) + 1e-6f);
        }
        // float4 element (k4 = lane>>2, colp), component lane&3
        cf[((size_t)(lane >> 2) * NN + colp) * 4 + (lane & 3)] = v;
    }
}

// ---------------------------------------------------------------------------
// K3: GEMM-argmax. R21: SPLIT-K ACROSS WAVES -- reuse without fat waves.
// Post-mortems R2..R5: dur ~= L1_floor/eff(occ). Reuse lived in per-wave
// registers, so reuse and occupancy were mutually exclusive; every RPW=8
// attempt died (VGPR 52 serialization / LDS barrier drain / VGPR 164 ILP
// collapse). This structure gets both:
//  - MROWS=8 rows per BLOCK, shared by its 4 waves (block-level reuse 8:
//    L2/L1 traffic 537MB, floor ~14us ~= VALU floor 14us).
//  - wave w sweeps interleaved 128-col tiles t = w, w+4, ... (J=2: cv[2]=8
//    VGPR, acc[8][2]=16 VGPR -- allocator-friendly ~50-70 VGPR total).
//  - grid 4096 (2048 active) -> 8 blocks/CU, ~32 waves/CU: TLP latency
//    hiding, not the ILP bet that failed 3x.
//  - per-column FMA chain k4-ascending/xyzw: BIT-IDENTICAL sums. Only the
//    max combine changes: per-wave maxima merged via 128B LDS + 1 barrier
//    (fmax is order-insensitive; winner set identical). Each wave then
//    ballot-emits its own disjoint col subset; msk bits already global
//    (colp>>6), so no index translation.
//  - rv: readfirstlane'd row tokens -> scalar s_load (proven R1/R3 path).
//  - NO min-waves launch_bounds (R2: capped VGPR 32 and serialized).
// ---------------------------------------------------------------------------
template <int J>
__device__ __forceinline__ void tile_body(const float4* __restrict__ x4,
                                          const float4* __restrict__ cm,
                                          const int* rtok, int cstart, int K,
                                          int lane, float* tmax,
                                          unsigned long long* msk) {
    float acc[MROWS][J];
#pragma unroll
    for (int r = 0; r < MROWS; ++r)
#pragma unroll
        for (int j = 0; j < J; ++j) acc[r][j] = 0.0f;

#pragma unroll 2
    for (int k4 = 0; k4 < 16; ++k4) {
        float4 rv[MROWS];
#pragma unroll
        for (int r = 0; r < MROWS; ++r)         // wave-uniform -> s_load
            rv[r] = x4[(size_t)rtok[r] * 16 + k4];
        const float4* cmk = cm + (size_t)k4 * NN + cstart + lane;
        float4 cv[J];
#pragma unroll
        for (int j = 0; j < J; ++j)             // coalesced b128 streams
            cv[j] = cmk[j * 64];
#pragma unroll
        for (int r = 0; r < MROWS; ++r)
#pragma unroll
            for (int j = 0; j < J; ++j)
                acc[r][j] = fmaf(rv[r].x, cv[j].x,
                            fmaf(rv[r].y, cv[j].y,
                            fmaf(rv[r].z, cv[j].z,
                            fmaf(rv[r].w, cv[j].w, acc[r][j]))));
    }

    const int cb0 = cstart >> 6;
#pragma unroll
    for (int r = 0; r < MROWS; ++r)
#pragma unroll
        for (int j = 0; j < J; ++j) {
            int colp = cstart + j * 64 + lane;
            float s = (colp < K) ? acc[r][j] : -1.0e30f;
            unsigned long long bit = 1ull << (cb0 + j);
            if (s > tmax[r])       { tmax[r] = s; msk[r] = bit; }
            else if (s == tmax[r])  msk[r] |= bit;
        }
}

__global__ __launch_bounds__(TPB) void k_argmax(
    const float* __restrict__ x,      // [B,N,C]
    const float4* __restrict__ colM,  // [B,16,N] float4
    const int*   __restrict__ cntP,
    const int*   __restrict__ cntK,
    const int*   __restrict__ listP,
    const int*   __restrict__ listK,
    float* __restrict__ S,            // [B,N]   zeroed by k_pre
    float* __restrict__ A) {          // [B,N,C] zeroed by k_pre; aliases d_out

    const int b    = blockIdx.x & 15;
    const int tile = blockIdx.x >> 4;
    const int P = cntP[b], K = cntK[b];
    const int base = tile * MROWS;
    if (base >= P) return;            // block-uniform; no barrier skipped

    const int tid = threadIdx.x;
    const int wid = tid >> 6;
    const int lane = tid & 63;

    int rtok[MROWS];
#pragma unroll
    for (int r = 0; r < MROWS; ++r) {
        int rid = base + r;
        int tok = (rid < P) ? listP[b * NN + rid] : 0;
        rtok[r] = __builtin_amdgcn_readfirstlane(tok);
    }
    const float4* x4 = (const float4*)(x + (size_t)b * NN * CC);
    const float4* cm = colM + (size_t)b * 16 * NN;

    float              tmax[MROWS];
    unsigned long long msk[MROWS];
#pragma unroll
    for (int r = 0; r < MROWS; ++r) { tmax[r] = -3.0e38f; msk[r] = 0ull; }

    // Split-K: wave wid owns 128-col tiles t = wid, wid+4, ... (disjoint).
    const int NT = (K + 127) >> 7;
    for (int t = wid; t < NT; t += 4)
        tile_body<2>(x4, cm, rtok, t << 7, K, lane, tmax, msk);

    // ---- merge per-wave maxima across the block (128B LDS, 1 barrier) ----
    __shared__ float mW[MROWS][4];
    const int nvr = min(MROWS, P - base);
#pragma unroll
    for (int r = 0; r < MROWS; ++r) {
        float m = tmax[r];
#pragma unroll
        for (int off = 32; off; off >>= 1) m = fmaxf(m, __shfl_xor(m, off, 64));
        if (lane == 0) mW[r][wid] = m;
    }
    __syncthreads();

    // ---- edge emission: each wave emits its own disjoint col subset ----
    for (int r = 0; r < nvr; ++r) {
        float M = fmaxf(fmaxf(mW[r][0], mW[r][1]), fmaxf(mW[r][2], mW[r][3]));
        unsigned long long bal = __ballot(tmax[r] == M && msk[r] != 0ull);
        if (bal == 0ull) continue;            // this wave holds no winners
        int src = rtok[r];
        float xv = x[(size_t)(b * NN + src) * CC + lane];
        float sq = xv * xv;
#pragma unroll
        for (int off = 32; off; off >>= 1) sq += __shfl_xor(sq, off, 64);
        float ivr = 1.0f / (sqrtf(sq) + 1e-6f);
        float wgt = expf(M * ivr);
        while (bal) {
            int sl = __ffsll(bal) - 1;
            bal &= bal - 1;
            unsigned long long mm = __shfl(msk[r], sl);
            while (mm) {
                int cb = __ffsll(mm) - 1;
                mm &= mm - 1;
                int colp = (cb << 6) + sl;
                int dst = listK[b * NN + colp];
                atomicAdd(&A[(size_t)(b * NN + dst) * CC + lane], wgt * xv);
                if (lane == 0) atomicAdd(&S[b * NN + dst], wgt);
            }
        }
    }
}

// ---------------------------------------------------------------------------
// K4: out = (e*x + A) / (e + S).  A aliases d_out (in-place), float4.
// ---------------------------------------------------------------------------
__global__ __launch_bounds__(TPB) void k_finalize(const float* __restrict__ x,
                                                  const float* __restrict__ S,
                                                  float* __restrict__ out) {
    int i = blockIdx.x * TPB + threadIdx.x;
    int row = i >> 4;
    float inv = 1.0f / (E_CONST + S[row]);
    float4 xv = ((const float4*)x)[i];
    float4 av = ((float4*)out)[i];
    float4 o;
    o.x = (xv.x * E_CONST + av.x) * inv;
    o.y = (xv.y * E_CONST + av.y) * inv;
    o.z = (xv.z * E_CONST + av.z) * inv;
    o.w = (xv.w * E_CONST + av.w) * inv;
    ((float4*)out)[i] = o;
}

// ---------------------------------------------------------------------------
extern "C" void kernel_launch(void* const* d_in, const int* in_sizes, int n_in,
                              void* d_out, int out_size, void* d_ws, size_t ws_size,
                              hipStream_t stream) {
    const float* x    = (const float*)d_in[0];
    const float* keep = (const float*)d_in[2];
    float* out = (float*)d_out;

    // ws: (reserved 128KB) | S 128KB | cnts 128B | listP 128KB | listK 128KB | colM 8MB
    char* ws = (char*)d_ws;
    float* S    = (float*)(ws + (128 << 10));
    int*   cntP = (int*)(ws + (256 << 10));
    int*   cntK = cntP + 16;
    int*   listP = (int*)(ws + (256 << 10) + 128);
    int*   listK = listP + BB * NN;
    float* colMf = (float*)(ws + (1 << 20));

    k_pre<<<512, TPB, 0, stream>>>(keep, out, S, cntP, cntK, listP, listK);

    // 1-D grid, b = id&15: colM written on the XCD that k_argmax reads it on.
    k_pre2<<<BB * 64, TPB, 0, stream>>>(x, cntK, listK, colMf);

    // 1-D grid: b = id & 15 (XCD pinning), tile = id >> 4.
    k_argmax<<<(NN / MROWS) * BB, TPB, 0, stream>>>(x, (const float4*)colMf,
                                                    cntP, cntK, listP, listK,
                                                    S, out);

    k_finalize<<<(BB * NN * CC / 4) / TPB, TPB, 0, stream>>>(x, S, out);
}